// Round 1
// baseline (3426.120 us; speedup 1.0000x reference)
//
#include <hip/hip_runtime.h>
#include <cstddef>

typedef __bf16 bf16;
typedef bf16 bf16x8 __attribute__((ext_vector_type(8)));
typedef float f32x4 __attribute__((ext_vector_type(4)));

#define N_NODES 50000
#define N_EDGES 800000
#define HID 128
#define NF 128
#define EC 100
#define NBLK 6
#define IN_DIM 5
#define LN2 0.69314718055994530942f
#define LDST 136  // 128 + 8 bf16 pad: breaks b128 row-stride bank aliasing

__device__ __forceinline__ float ssp_f(float v) {
  float e = __expf(-fabsf(v));
  return fmaxf(v, 0.0f) + __logf(1.0f + e) - LN2;
}

__device__ __forceinline__ f32x4 zero4() {
  f32x4 v; v[0] = 0.f; v[1] = 0.f; v[2] = 0.f; v[3] = 0.f; return v;
}

// h[n][c] = sum_k zf[n][k]*W[k][c] + b[c] + ptemb[n][c]
__global__ void embed_kernel(const float* __restrict__ z,
                             const float* __restrict__ ew,
                             const float* __restrict__ eb,
                             float* __restrict__ h) {
  int i = blockIdx.x * 256 + threadIdx.x;
  if (i >= N_NODES * HID) return;
  int n = i >> 7, c = i & 127;
  const float* zr = z + (size_t)n * (IN_DIM + HID);
  float acc = eb[c] + zr[IN_DIM + c];
#pragma unroll
  for (int k = 0; k < IN_DIM; k++) acc = fmaf(zr[k], ew[k * HID + c], acc);
  h[i] = acc;
}

__global__ void zero_kernel(float4* __restrict__ p, int n4) {
  int i = blockIdx.x * 256 + threadIdx.x;
  if (i < n4) p[i] = make_float4(0.f, 0.f, 0.f, 0.f);
}

// x = h @ w  (64-row tiles, bf16 MFMA 16x16x32, wave w owns cols [32w,32w+32))
__global__ __launch_bounds__(256, 2)
void xgemm_kernel(const float* __restrict__ hmat,
                  const float* __restrict__ w,
                  float* __restrict__ xout) {
  __shared__ bf16 sA[64 * LDST];
  const int tid = threadIdx.x;
  const int wave = tid >> 6, lane = tid & 63;
  const int quad = lane >> 4, lanelo = lane & 15;
  const int ncol0 = wave * 32;

  // B fragments in registers: B[k = ks*32+quad*8+j][n]
  bf16x8 Bf[2][4];
#pragma unroll
  for (int nt = 0; nt < 2; nt++) {
    int n = ncol0 + nt * 16 + lanelo;
#pragma unroll
    for (int ks = 0; ks < 4; ks++) {
      int k0 = ks * 32 + quad * 8;
      bf16x8 f;
#pragma unroll
      for (int j = 0; j < 8; j++) f[j] = (bf16)w[(k0 + j) * NF + n];
      Bf[nt][ks] = f;
    }
  }

  const int ntiles = (N_NODES + 63) / 64;
  for (int tile = blockIdx.x; tile < ntiles; tile += gridDim.x) {
    const int row0 = tile * 64;
    for (int idx = tid; idx < 64 * 128 / 4; idx += 256) {
      int flat = idx * 4;
      int r = flat >> 7, c = flat & 127;
      int grow = row0 + r;
      float4 v = (grow < N_NODES) ? *(const float4*)&hmat[(size_t)grow * HID + c]
                                  : make_float4(0.f, 0.f, 0.f, 0.f);
      bf16* dp = &sA[r * LDST + c];
      dp[0] = (bf16)v.x; dp[1] = (bf16)v.y; dp[2] = (bf16)v.z; dp[3] = (bf16)v.w;
    }
    __syncthreads();

    f32x4 acc[4][2];
#pragma unroll
    for (int mt = 0; mt < 4; mt++)
#pragma unroll
      for (int nt = 0; nt < 2; nt++) acc[mt][nt] = zero4();
#pragma unroll
    for (int ks = 0; ks < 4; ks++) {
      bf16x8 a[4];
#pragma unroll
      for (int mt = 0; mt < 4; mt++)
        a[mt] = *(const bf16x8*)&sA[(mt * 16 + lanelo) * LDST + ks * 32 + quad * 8];
#pragma unroll
      for (int mt = 0; mt < 4; mt++)
#pragma unroll
        for (int nt = 0; nt < 2; nt++)
          acc[mt][nt] = __builtin_amdgcn_mfma_f32_16x16x32_bf16(a[mt], Bf[nt][ks], acc[mt][nt], 0, 0, 0);
    }
    // C/D layout: row = quad*4 + reg, col = lanelo (within 16x16 tile)
#pragma unroll
    for (int mt = 0; mt < 4; mt++)
#pragma unroll
      for (int r = 0; r < 4; r++) {
        int grow = row0 + mt * 16 + quad * 4 + r;
        if (grow < N_NODES) {
#pragma unroll
          for (int nt = 0; nt < 2; nt++)
            xout[(size_t)grow * NF + ncol0 + nt * 16 + lanelo] = acc[mt][nt][r];
        }
      }
    __syncthreads();  // protect sA before next tile's staging
  }
}

// Fused edge MLP + gather + mask + scatter-add:
// W = ssp(ea@w1+b1)@w2+b2; msg = x[src]*W*C; agg[dst] += msg
__global__ __launch_bounds__(256, 2)
void edge_kernel(const float* __restrict__ ea,
                 const int* __restrict__ ei,
                 const float* __restrict__ elen,
                 const float* __restrict__ w1, const float* __restrict__ b1,
                 const float* __restrict__ w2, const float* __restrict__ b2,
                 const float* __restrict__ x,
                 float* __restrict__ agg) {
  __shared__ bf16 sA[64 * LDST];
  __shared__ bf16 sT[64 * LDST];
  __shared__ int s_src[64];
  __shared__ int s_dst[64];
  __shared__ float s_c[64];

  const int tid = threadIdx.x;
  const int wave = tid >> 6, lane = tid & 63;
  const int quad = lane >> 4, lanelo = lane & 15;
  const int ncol0 = wave * 32;

  bf16x8 Bf1[2][4], Bf2[2][4];
#pragma unroll
  for (int nt = 0; nt < 2; nt++) {
    int n = ncol0 + nt * 16 + lanelo;
#pragma unroll
    for (int ks = 0; ks < 4; ks++) {
      int k0 = ks * 32 + quad * 8;
      bf16x8 f1, f2;
#pragma unroll
      for (int j = 0; j < 8; j++) {
        int k = k0 + j;
        f1[j] = (bf16)((k < EC) ? w1[k * NF + n] : 0.0f);  // pad K 100->128
        f2[j] = (bf16)w2[k * NF + n];
      }
      Bf1[nt][ks] = f1; Bf2[nt][ks] = f2;
    }
  }
  float bias1[2], bias2[2];
#pragma unroll
  for (int nt = 0; nt < 2; nt++) {
    bias1[nt] = b1[ncol0 + nt * 16 + lanelo];
    bias2[nt] = b2[ncol0 + nt * 16 + lanelo];
  }

  // zero the K-pad region of sA once (never overwritten by staging)
  for (int idx = tid; idx < 64 * (NF - EC); idx += 256) {
    int r = idx / (NF - EC), c = EC + idx % (NF - EC);
    sA[r * LDST + c] = (bf16)0.0f;
  }

  const int ntiles = N_EDGES / 64;  // 12500 exact
  for (int tile = blockIdx.x; tile < ntiles; tile += gridDim.x) {
    const int e0 = tile * 64;
    for (int idx = tid; idx < 64 * EC; idx += 256) {
      int r = idx / EC, c = idx - r * EC;
      sA[r * LDST + c] = (bf16)ea[(size_t)(e0 + r) * EC + c];
    }
    if (tid < 64) {
      int e = e0 + tid;
      s_src[tid] = ei[e];
      s_dst[tid] = ei[N_EDGES + e];
      float L = elen[e];
      s_c[tid] = (L <= 10.0f && L >= 0.0f) ? 1.0f : 0.0f;
    }
    __syncthreads();

    // GEMM1: t = ea @ w1
    f32x4 acc[4][2];
#pragma unroll
    for (int mt = 0; mt < 4; mt++)
#pragma unroll
      for (int nt = 0; nt < 2; nt++) acc[mt][nt] = zero4();
#pragma unroll
    for (int ks = 0; ks < 4; ks++) {
      bf16x8 a[4];
#pragma unroll
      for (int mt = 0; mt < 4; mt++)
        a[mt] = *(const bf16x8*)&sA[(mt * 16 + lanelo) * LDST + ks * 32 + quad * 8];
#pragma unroll
      for (int mt = 0; mt < 4; mt++)
#pragma unroll
        for (int nt = 0; nt < 2; nt++)
          acc[mt][nt] = __builtin_amdgcn_mfma_f32_16x16x32_bf16(a[mt], Bf1[nt][ks], acc[mt][nt], 0, 0, 0);
    }
    // ssp, C-layout -> A-layout via LDS
#pragma unroll
    for (int mt = 0; mt < 4; mt++)
#pragma unroll
      for (int nt = 0; nt < 2; nt++)
#pragma unroll
        for (int r = 0; r < 4; r++) {
          float v = ssp_f(acc[mt][nt][r] + bias1[nt]);
          sT[(mt * 16 + quad * 4 + r) * LDST + ncol0 + nt * 16 + lanelo] = (bf16)v;
        }
    __syncthreads();

    // GEMM2: W = t @ w2
#pragma unroll
    for (int mt = 0; mt < 4; mt++)
#pragma unroll
      for (int nt = 0; nt < 2; nt++) acc[mt][nt] = zero4();
#pragma unroll
    for (int ks = 0; ks < 4; ks++) {
      bf16x8 a[4];
#pragma unroll
      for (int mt = 0; mt < 4; mt++)
        a[mt] = *(const bf16x8*)&sT[(mt * 16 + lanelo) * LDST + ks * 32 + quad * 8];
#pragma unroll
      for (int mt = 0; mt < 4; mt++)
#pragma unroll
        for (int nt = 0; nt < 2; nt++)
          acc[mt][nt] = __builtin_amdgcn_mfma_f32_16x16x32_bf16(a[mt], Bf2[nt][ks], acc[mt][nt], 0, 0, 0);
    }
    // epilogue: msg = x[src]*W*C, atomic scatter to agg[dst]
#pragma unroll
    for (int mt = 0; mt < 4; mt++)
#pragma unroll
      for (int r = 0; r < 4; r++) {
        int row = mt * 16 + quad * 4 + r;
        float ce = s_c[row];
        if (ce != 0.0f) {
          int srcn = s_src[row], dstn = s_dst[row];
#pragma unroll
          for (int nt = 0; nt < 2; nt++) {
            int col = ncol0 + nt * 16 + lanelo;
            float wv = acc[mt][nt][r] + bias2[nt];
            float msg = wv * x[(size_t)srcn * NF + col];
            atomicAdd(&agg[(size_t)dstn * NF + col], msg);
          }
        }
      }
    __syncthreads();  // meta arrays read by all waves before next staging
  }
}

// h += ssp(agg@w1+b1)@w2 + b2   (two fused GEMMs, same structure as edge_kernel)
__global__ __launch_bounds__(256, 2)
void node_kernel(const float* __restrict__ agg,
                 const float* __restrict__ w1, const float* __restrict__ b1,
                 const float* __restrict__ w2, const float* __restrict__ b2,
                 float* __restrict__ h) {
  __shared__ bf16 sA[64 * LDST];
  __shared__ bf16 sT[64 * LDST];
  const int tid = threadIdx.x;
  const int wave = tid >> 6, lane = tid & 63;
  const int quad = lane >> 4, lanelo = lane & 15;
  const int ncol0 = wave * 32;

  bf16x8 Bf1[2][4], Bf2[2][4];
#pragma unroll
  for (int nt = 0; nt < 2; nt++) {
    int n = ncol0 + nt * 16 + lanelo;
#pragma unroll
    for (int ks = 0; ks < 4; ks++) {
      int k0 = ks * 32 + quad * 8;
      bf16x8 f1, f2;
#pragma unroll
      for (int j = 0; j < 8; j++) {
        int k = k0 + j;
        f1[j] = (bf16)w1[k * HID + n];
        f2[j] = (bf16)w2[k * HID + n];
      }
      Bf1[nt][ks] = f1; Bf2[nt][ks] = f2;
    }
  }
  float bias1[2], bias2[2];
#pragma unroll
  for (int nt = 0; nt < 2; nt++) {
    bias1[nt] = b1[ncol0 + nt * 16 + lanelo];
    bias2[nt] = b2[ncol0 + nt * 16 + lanelo];
  }

  const int ntiles = (N_NODES + 63) / 64;
  for (int tile = blockIdx.x; tile < ntiles; tile += gridDim.x) {
    const int row0 = tile * 64;
    for (int idx = tid; idx < 64 * 128 / 4; idx += 256) {
      int flat = idx * 4;
      int r = flat >> 7, c = flat & 127;
      int grow = row0 + r;
      float4 v = (grow < N_NODES) ? *(const float4*)&agg[(size_t)grow * NF + c]
                                  : make_float4(0.f, 0.f, 0.f, 0.f);
      bf16* dp = &sA[r * LDST + c];
      dp[0] = (bf16)v.x; dp[1] = (bf16)v.y; dp[2] = (bf16)v.z; dp[3] = (bf16)v.w;
    }
    __syncthreads();

    f32x4 acc[4][2];
#pragma unroll
    for (int mt = 0; mt < 4; mt++)
#pragma unroll
      for (int nt = 0; nt < 2; nt++) acc[mt][nt] = zero4();
#pragma unroll
    for (int ks = 0; ks < 4; ks++) {
      bf16x8 a[4];
#pragma unroll
      for (int mt = 0; mt < 4; mt++)
        a[mt] = *(const bf16x8*)&sA[(mt * 16 + lanelo) * LDST + ks * 32 + quad * 8];
#pragma unroll
      for (int mt = 0; mt < 4; mt++)
#pragma unroll
        for (int nt = 0; nt < 2; nt++)
          acc[mt][nt] = __builtin_amdgcn_mfma_f32_16x16x32_bf16(a[mt], Bf1[nt][ks], acc[mt][nt], 0, 0, 0);
    }
#pragma unroll
    for (int mt = 0; mt < 4; mt++)
#pragma unroll
      for (int nt = 0; nt < 2; nt++)
#pragma unroll
        for (int r = 0; r < 4; r++) {
          float v = ssp_f(acc[mt][nt][r] + bias1[nt]);
          sT[(mt * 16 + quad * 4 + r) * LDST + ncol0 + nt * 16 + lanelo] = (bf16)v;
        }
    __syncthreads();

#pragma unroll
    for (int mt = 0; mt < 4; mt++)
#pragma unroll
      for (int nt = 0; nt < 2; nt++) acc[mt][nt] = zero4();
#pragma unroll
    for (int ks = 0; ks < 4; ks++) {
      bf16x8 a[4];
#pragma unroll
      for (int mt = 0; mt < 4; mt++)
        a[mt] = *(const bf16x8*)&sT[(mt * 16 + lanelo) * LDST + ks * 32 + quad * 8];
#pragma unroll
      for (int mt = 0; mt < 4; mt++)
#pragma unroll
        for (int nt = 0; nt < 2; nt++)
          acc[mt][nt] = __builtin_amdgcn_mfma_f32_16x16x32_bf16(a[mt], Bf2[nt][ks], acc[mt][nt], 0, 0, 0);
    }
#pragma unroll
    for (int mt = 0; mt < 4; mt++)
#pragma unroll
      for (int r = 0; r < 4; r++) {
        int grow = row0 + mt * 16 + quad * 4 + r;
        if (grow < N_NODES) {
#pragma unroll
          for (int nt = 0; nt < 2; nt++) {
            int col = ncol0 + nt * 16 + lanelo;
            size_t off = (size_t)grow * HID + col;
            h[off] += acc[mt][nt][r] + bias2[nt];
          }
        }
      }
    __syncthreads();
  }
}

extern "C" void kernel_launch(void* const* d_in, const int* in_sizes, int n_in,
                              void* d_out, int out_size, void* d_ws, size_t ws_size,
                              hipStream_t stream) {
  const float* z        = (const float*)d_in[0];
  const int*   ei       = (const int*)d_in[1];
  const float* elen     = (const float*)d_in[2];
  const float* ea       = (const float*)d_in[3];
  const float* emblin_w = (const float*)d_in[4];
  const float* emblin_b = (const float*)d_in[5];
  const float* lin1_w   = (const float*)d_in[6];
  const float* nn_w1    = (const float*)d_in[7];
  const float* nn_b1    = (const float*)d_in[8];
  const float* nn_w2    = (const float*)d_in[9];
  const float* nn_b2    = (const float*)d_in[10];
  const float* lin2_w   = (const float*)d_in[11];
  const float* lin2_b   = (const float*)d_in[12];
  const float* lin_w    = (const float*)d_in[13];
  const float* lin_b    = (const float*)d_in[14];

  float* h   = (float*)d_out;                       // 50000 x 128
  float* x   = (float*)d_ws;                        // 50000 x 128
  float* agg = x + (size_t)N_NODES * NF;            // 50000 x 128

  embed_kernel<<<(N_NODES * HID + 255) / 256, 256, 0, stream>>>(z, emblin_w, emblin_b, h);

  for (int i = 0; i < NBLK; i++) {
    xgemm_kernel<<<782, 256, 0, stream>>>(h, lin1_w + (size_t)i * HID * NF, x);
    zero_kernel<<<(N_NODES * NF / 4 + 255) / 256, 256, 0, stream>>>((float4*)agg, N_NODES * NF / 4);
    edge_kernel<<<2048, 256, 0, stream>>>(ea, ei, elen,
        nn_w1 + (size_t)i * EC * NF, nn_b1 + (size_t)i * NF,
        nn_w2 + (size_t)i * NF * NF, nn_b2 + (size_t)i * NF,
        x, agg);
    node_kernel<<<782, 256, 0, stream>>>(agg,
        lin2_w + (size_t)i * NF * HID, lin2_b + (size_t)i * HID,
        lin_w + (size_t)i * HID * HID, lin_b + (size_t)i * HID,
        h);
  }
}

// Round 2
// 3014.392 us; speedup vs baseline: 1.1366x; 1.1366x over previous
//
#include <hip/hip_runtime.h>
#include <cstddef>

typedef __bf16 bf16;
typedef bf16 bf16x4 __attribute__((ext_vector_type(4)));
typedef bf16 bf16x8 __attribute__((ext_vector_type(8)));
typedef float f32x4 __attribute__((ext_vector_type(4)));

#define N_NODES 50000
#define N_EDGES 800000
#define HID 128
#define NF 128
#define EC 100
#define NBLK 6
#define IN_DIM 5
#define LN2 0.69314718055994530942f
#define LDST 136          // 128 + 8 bf16 pad: keeps 16B row alignment, breaks bank aliasing
#define FRAG_ELEMS 16384  // one repacked 128x128 weight: 2048 frags x 8 bf16

__device__ __forceinline__ float ssp_f(float v) {
  float e = __expf(-fabsf(v));
  return fmaxf(v, 0.0f) + __logf(1.0f + e) - LN2;
}

__device__ __forceinline__ f32x4 zero4() {
  f32x4 v; v[0] = 0.f; v[1] = 0.f; v[2] = 0.f; v[3] = 0.f; return v;
}

// Repack a [K<=128 x 128] fp32 weight into per-lane MFMA B-fragment order (bf16).
// Consumer: Bf[nt][ks] element j = W[k=ks*32+quad*8+j][n=wave*32+nt*16+lanelo].
// Frag array index: ((wave*2+nt)*4+ks)*64 + lane  -> 16B per frag, lane-coalesced.
__global__ void repack_kernel(const float* __restrict__ src, bf16* __restrict__ dst,
                              int K, int srcStride) {
  const int m = blockIdx.x;  // which of the 6 layer-blocks
  const float* s = src + (size_t)m * srcStride;
  bf16* d = dst + (size_t)m * FRAG_ELEMS;
  const int tid = threadIdx.x;
  const int wave = tid >> 6, lane = tid & 63;
  const int quad = lane >> 4, lanelo = lane & 15;
  const int col = wave * 32 + lanelo;  // + nt*16 below
#pragma unroll
  for (int nt = 0; nt < 2; nt++)
#pragma unroll
    for (int ks = 0; ks < 4; ks++) {
      bf16x8 f;
#pragma unroll
      for (int j = 0; j < 8; j++) {
        int k = ks * 32 + quad * 8 + j;
        f[j] = (bf16)((k < K) ? s[(size_t)k * 128 + col + nt * 16] : 0.0f);
      }
      *(bf16x8*)&d[(size_t)(((wave * 2 + nt) * 4 + ks) * 64 + lane) * 8] = f;
    }
}

// h[n][c] = sum_k zf[n][k]*W[k][c] + b[c] + ptemb[n][c]
__global__ void embed_kernel(const float* __restrict__ z,
                             const float* __restrict__ ew,
                             const float* __restrict__ eb,
                             float* __restrict__ h) {
  int i = blockIdx.x * 256 + threadIdx.x;
  if (i >= N_NODES * HID) return;
  int n = i >> 7, c = i & 127;
  const float* zr = z + (size_t)n * (IN_DIM + HID);
  float acc = eb[c] + zr[IN_DIM + c];
#pragma unroll
  for (int k = 0; k < IN_DIM; k++) acc = fmaf(zr[k], ew[k * HID + c], acc);
  h[i] = acc;
}

__global__ void zero_kernel(float4* __restrict__ p, int n4) {
  int i = blockIdx.x * 256 + threadIdx.x;
  if (i < n4) p[i] = make_float4(0.f, 0.f, 0.f, 0.f);
}

// x = h @ w  (one 64-row tile per block; wave w owns cols [32w,32w+32))
__global__ __launch_bounds__(256, 4)
void xgemm_kernel(const float* __restrict__ hmat,
                  const bf16* __restrict__ wf,
                  float* __restrict__ xout) {
  __shared__ bf16 sA[64 * LDST];
  const int tid = threadIdx.x;
  const int wave = tid >> 6, lane = tid & 63;
  const int quad = lane >> 4, lanelo = lane & 15;
  const int ncol0 = wave * 32;
  const int row0 = blockIdx.x * 64;

  bf16x8 Bf[2][4];
#pragma unroll
  for (int nt = 0; nt < 2; nt++)
#pragma unroll
    for (int ks = 0; ks < 4; ks++)
      Bf[nt][ks] = *(const bf16x8*)&wf[(size_t)(((wave * 2 + nt) * 4 + ks) * 64 + lane) * 8];

#pragma unroll
  for (int it = 0; it < 8; it++) {
    int idx = tid + it * 256;         // 64 rows x 32 float4-chunks
    int r = idx >> 5, c4 = idx & 31;
    int grow = row0 + r;
    float4 v = (grow < N_NODES) ? *(const float4*)&hmat[(size_t)grow * HID + c4 * 4]
                                : make_float4(0.f, 0.f, 0.f, 0.f);
    bf16x4 o; o[0] = (bf16)v.x; o[1] = (bf16)v.y; o[2] = (bf16)v.z; o[3] = (bf16)v.w;
    *(bf16x4*)&sA[r * LDST + c4 * 4] = o;
  }
  __syncthreads();

  f32x4 acc[4][2];
#pragma unroll
  for (int mt = 0; mt < 4; mt++)
#pragma unroll
    for (int nt = 0; nt < 2; nt++) acc[mt][nt] = zero4();
#pragma unroll
  for (int ks = 0; ks < 4; ks++) {
    bf16x8 a[4];
#pragma unroll
    for (int mt = 0; mt < 4; mt++)
      a[mt] = *(const bf16x8*)&sA[(mt * 16 + lanelo) * LDST + ks * 32 + quad * 8];
#pragma unroll
    for (int mt = 0; mt < 4; mt++)
#pragma unroll
      for (int nt = 0; nt < 2; nt++)
        acc[mt][nt] = __builtin_amdgcn_mfma_f32_16x16x32_bf16(a[mt], Bf[nt][ks], acc[mt][nt], 0, 0, 0);
  }
  // C/D layout: row = quad*4 + reg, col = lanelo (within each 16x16 tile)
#pragma unroll
  for (int mt = 0; mt < 4; mt++)
#pragma unroll
    for (int r = 0; r < 4; r++) {
      int grow = row0 + mt * 16 + quad * 4 + r;
      if (grow < N_NODES) {
#pragma unroll
        for (int nt = 0; nt < 2; nt++)
          xout[(size_t)grow * NF + ncol0 + nt * 16 + lanelo] = acc[mt][nt][r];
      }
    }
}

// Fused edge MLP + gather + mask + scatter-add. One 64-edge tile per block.
// Single LDS buffer: ea-tile (GEMM1 A) is overwritten in-place by ssp(t) (GEMM2 A).
__global__ __launch_bounds__(256, 4)
void edge_kernel(const float* __restrict__ ea,
                 const int* __restrict__ ei,
                 const float* __restrict__ elen,
                 const bf16* __restrict__ w1f, const float* __restrict__ b1,
                 const bf16* __restrict__ w2f, const float* __restrict__ b2,
                 const float* __restrict__ x,
                 float* __restrict__ agg) {
  __shared__ bf16 sA[64 * LDST];
  __shared__ int s_src[64];
  __shared__ int s_dst[64];
  __shared__ float s_c[64];

  const int tid = threadIdx.x;
  const int wave = tid >> 6, lane = tid & 63;
  const int quad = lane >> 4, lanelo = lane & 15;
  const int ncol0 = wave * 32;
  const int e0 = blockIdx.x * 64;

  // B fragments: 16 coalesced b128 loads (repacked), issued early to overlap staging
  bf16x8 Bf1[2][4], Bf2[2][4];
#pragma unroll
  for (int nt = 0; nt < 2; nt++)
#pragma unroll
    for (int ks = 0; ks < 4; ks++) {
      size_t fo = (size_t)(((wave * 2 + nt) * 4 + ks) * 64 + lane) * 8;
      Bf1[nt][ks] = *(const bf16x8*)&w1f[fo];
      Bf2[nt][ks] = *(const bf16x8*)&w2f[fo];
    }
  float bias1[2], bias2[2];
#pragma unroll
  for (int nt = 0; nt < 2; nt++) {
    bias1[nt] = b1[ncol0 + nt * 16 + lanelo];
    bias2[nt] = b2[ncol0 + nt * 16 + lanelo];
  }

  // stage edge_attr tile: 64 x 100 fp32 -> 64 x 128 bf16 (cols 100..127 zero)
  // EC=100 = exactly 25 float4 chunks per row; chunks 25..31 write zeros.
#pragma unroll
  for (int it = 0; it < 8; it++) {
    int idx = tid + it * 256;
    int r = idx >> 5, c4 = idx & 31;
    float4 v = make_float4(0.f, 0.f, 0.f, 0.f);
    if (c4 < 25) v = *(const float4*)&ea[(size_t)(e0 + r) * EC + c4 * 4];
    bf16x4 o; o[0] = (bf16)v.x; o[1] = (bf16)v.y; o[2] = (bf16)v.z; o[3] = (bf16)v.w;
    *(bf16x4*)&sA[r * LDST + c4 * 4] = o;
  }
  if (tid < 64) {
    int e = e0 + tid;
    s_src[tid] = ei[e];
    s_dst[tid] = ei[N_EDGES + e];
    float L = elen[e];
    s_c[tid] = (L <= 10.0f && L >= 0.0f) ? 1.0f : 0.0f;
  }
  __syncthreads();

  // GEMM1: t = ea @ w1
  f32x4 acc[4][2];
#pragma unroll
  for (int mt = 0; mt < 4; mt++)
#pragma unroll
    for (int nt = 0; nt < 2; nt++) acc[mt][nt] = zero4();
#pragma unroll
  for (int ks = 0; ks < 4; ks++) {
    bf16x8 a[4];
#pragma unroll
    for (int mt = 0; mt < 4; mt++)
      a[mt] = *(const bf16x8*)&sA[(mt * 16 + lanelo) * LDST + ks * 32 + quad * 8];
#pragma unroll
    for (int mt = 0; mt < 4; mt++)
#pragma unroll
      for (int nt = 0; nt < 2; nt++)
        acc[mt][nt] = __builtin_amdgcn_mfma_f32_16x16x32_bf16(a[mt], Bf1[nt][ks], acc[mt][nt], 0, 0, 0);
  }
  __syncthreads();  // all waves done reading ea-tile before in-place overwrite

  // ssp, C-layout -> A-layout, written back into the same buffer
#pragma unroll
  for (int mt = 0; mt < 4; mt++)
#pragma unroll
    for (int nt = 0; nt < 2; nt++)
#pragma unroll
      for (int r = 0; r < 4; r++) {
        float v = ssp_f(acc[mt][nt][r] + bias1[nt]);
        sA[(mt * 16 + quad * 4 + r) * LDST + ncol0 + nt * 16 + lanelo] = (bf16)v;
      }
  __syncthreads();

  // GEMM2: W = t @ w2
#pragma unroll
  for (int mt = 0; mt < 4; mt++)
#pragma unroll
    for (int nt = 0; nt < 2; nt++) acc[mt][nt] = zero4();
#pragma unroll
  for (int ks = 0; ks < 4; ks++) {
    bf16x8 a[4];
#pragma unroll
    for (int mt = 0; mt < 4; mt++)
      a[mt] = *(const bf16x8*)&sA[(mt * 16 + lanelo) * LDST + ks * 32 + quad * 8];
#pragma unroll
    for (int mt = 0; mt < 4; mt++)
#pragma unroll
      for (int nt = 0; nt < 2; nt++)
        acc[mt][nt] = __builtin_amdgcn_mfma_f32_16x16x32_bf16(a[mt], Bf2[nt][ks], acc[mt][nt], 0, 0, 0);
  }

  // epilogue: msg = x[src]*W*C, atomic scatter to agg[dst]; block end drains atomics
#pragma unroll
  for (int mt = 0; mt < 4; mt++)
#pragma unroll
    for (int r = 0; r < 4; r++) {
      int row = mt * 16 + quad * 4 + r;
      float ce = s_c[row];
      if (ce != 0.0f) {
        int srcn = s_src[row], dstn = s_dst[row];
#pragma unroll
        for (int nt = 0; nt < 2; nt++) {
          int col = ncol0 + nt * 16 + lanelo;
          float wv = acc[mt][nt][r] + bias2[nt];
          float msg = wv * x[(size_t)srcn * NF + col];
          atomicAdd(&agg[(size_t)dstn * NF + col], msg);
        }
      }
    }
}

// h += ssp(agg@w1+b1)@w2 + b2  (one 64-row tile per block, single aliased buffer)
__global__ __launch_bounds__(256, 4)
void node_kernel(const float* __restrict__ agg,
                 const bf16* __restrict__ w1f, const float* __restrict__ b1,
                 const bf16* __restrict__ w2f, const float* __restrict__ b2,
                 float* __restrict__ h) {
  __shared__ bf16 sA[64 * LDST];
  const int tid = threadIdx.x;
  const int wave = tid >> 6, lane = tid & 63;
  const int quad = lane >> 4, lanelo = lane & 15;
  const int ncol0 = wave * 32;
  const int row0 = blockIdx.x * 64;

  bf16x8 Bf1[2][4], Bf2[2][4];
#pragma unroll
  for (int nt = 0; nt < 2; nt++)
#pragma unroll
    for (int ks = 0; ks < 4; ks++) {
      size_t fo = (size_t)(((wave * 2 + nt) * 4 + ks) * 64 + lane) * 8;
      Bf1[nt][ks] = *(const bf16x8*)&w1f[fo];
      Bf2[nt][ks] = *(const bf16x8*)&w2f[fo];
    }
  float bias1[2], bias2[2];
#pragma unroll
  for (int nt = 0; nt < 2; nt++) {
    bias1[nt] = b1[ncol0 + nt * 16 + lanelo];
    bias2[nt] = b2[ncol0 + nt * 16 + lanelo];
  }

#pragma unroll
  for (int it = 0; it < 8; it++) {
    int idx = tid + it * 256;
    int r = idx >> 5, c4 = idx & 31;
    int grow = row0 + r;
    float4 v = (grow < N_NODES) ? *(const float4*)&agg[(size_t)grow * NF + c4 * 4]
                                : make_float4(0.f, 0.f, 0.f, 0.f);
    bf16x4 o; o[0] = (bf16)v.x; o[1] = (bf16)v.y; o[2] = (bf16)v.z; o[3] = (bf16)v.w;
    *(bf16x4*)&sA[r * LDST + c4 * 4] = o;
  }
  __syncthreads();

  f32x4 acc[4][2];
#pragma unroll
  for (int mt = 0; mt < 4; mt++)
#pragma unroll
    for (int nt = 0; nt < 2; nt++) acc[mt][nt] = zero4();
#pragma unroll
  for (int ks = 0; ks < 4; ks++) {
    bf16x8 a[4];
#pragma unroll
    for (int mt = 0; mt < 4; mt++)
      a[mt] = *(const bf16x8*)&sA[(mt * 16 + lanelo) * LDST + ks * 32 + quad * 8];
#pragma unroll
    for (int mt = 0; mt < 4; mt++)
#pragma unroll
      for (int nt = 0; nt < 2; nt++)
        acc[mt][nt] = __builtin_amdgcn_mfma_f32_16x16x32_bf16(a[mt], Bf1[nt][ks], acc[mt][nt], 0, 0, 0);
  }
  __syncthreads();

#pragma unroll
  for (int mt = 0; mt < 4; mt++)
#pragma unroll
    for (int nt = 0; nt < 2; nt++)
#pragma unroll
      for (int r = 0; r < 4; r++) {
        float v = ssp_f(acc[mt][nt][r] + bias1[nt]);
        sA[(mt * 16 + quad * 4 + r) * LDST + ncol0 + nt * 16 + lanelo] = (bf16)v;
      }
  __syncthreads();

#pragma unroll
  for (int mt = 0; mt < 4; mt++)
#pragma unroll
    for (int nt = 0; nt < 2; nt++) acc[mt][nt] = zero4();
#pragma unroll
  for (int ks = 0; ks < 4; ks++) {
    bf16x8 a[4];
#pragma unroll
    for (int mt = 0; mt < 4; mt++)
      a[mt] = *(const bf16x8*)&sA[(mt * 16 + lanelo) * LDST + ks * 32 + quad * 8];
#pragma unroll
    for (int mt = 0; mt < 4; mt++)
#pragma unroll
      for (int nt = 0; nt < 2; nt++)
        acc[mt][nt] = __builtin_amdgcn_mfma_f32_16x16x32_bf16(a[mt], Bf2[nt][ks], acc[mt][nt], 0, 0, 0);
  }
#pragma unroll
  for (int mt = 0; mt < 4; mt++)
#pragma unroll
    for (int r = 0; r < 4; r++) {
      int grow = row0 + mt * 16 + quad * 4 + r;
      if (grow < N_NODES) {
#pragma unroll
        for (int nt = 0; nt < 2; nt++) {
          int col = ncol0 + nt * 16 + lanelo;
          size_t off = (size_t)grow * HID + col;
          h[off] += acc[mt][nt][r] + bias2[nt];
        }
      }
    }
}

extern "C" void kernel_launch(void* const* d_in, const int* in_sizes, int n_in,
                              void* d_out, int out_size, void* d_ws, size_t ws_size,
                              hipStream_t stream) {
  const float* z        = (const float*)d_in[0];
  const int*   ei       = (const int*)d_in[1];
  const float* elen     = (const float*)d_in[2];
  const float* ea       = (const float*)d_in[3];
  const float* emblin_w = (const float*)d_in[4];
  const float* emblin_b = (const float*)d_in[5];
  const float* lin1_w   = (const float*)d_in[6];
  const float* nn_w1    = (const float*)d_in[7];
  const float* nn_b1    = (const float*)d_in[8];
  const float* nn_w2    = (const float*)d_in[9];
  const float* nn_b2    = (const float*)d_in[10];
  const float* lin2_w   = (const float*)d_in[11];
  const float* lin2_b   = (const float*)d_in[12];
  const float* lin_w    = (const float*)d_in[13];
  const float* lin_b    = (const float*)d_in[14];

  float* h   = (float*)d_out;                       // 50000 x 128
  float* x   = (float*)d_ws;                        // 50000 x 128
  float* agg = x + (size_t)N_NODES * NF;            // 50000 x 128
  bf16* wp      = (bf16*)(agg + (size_t)N_NODES * NF);
  bf16* wp_lin1 = wp;                               // 6 x 16384 bf16 each
  bf16* wp_nw1  = wp + 1 * (size_t)NBLK * FRAG_ELEMS;
  bf16* wp_nw2  = wp + 2 * (size_t)NBLK * FRAG_ELEMS;
  bf16* wp_l2   = wp + 3 * (size_t)NBLK * FRAG_ELEMS;
  bf16* wp_l    = wp + 4 * (size_t)NBLK * FRAG_ELEMS;

  repack_kernel<<<NBLK, 256, 0, stream>>>(lin1_w, wp_lin1, HID, HID * NF);
  repack_kernel<<<NBLK, 256, 0, stream>>>(nn_w1, wp_nw1, EC, EC * NF);
  repack_kernel<<<NBLK, 256, 0, stream>>>(nn_w2, wp_nw2, NF, NF * NF);
  repack_kernel<<<NBLK, 256, 0, stream>>>(lin2_w, wp_l2, NF, NF * HID);
  repack_kernel<<<NBLK, 256, 0, stream>>>(lin_w, wp_l, HID, HID * HID);

  embed_kernel<<<(N_NODES * HID + 255) / 256, 256, 0, stream>>>(z, emblin_w, emblin_b, h);

  const int node_tiles = (N_NODES + 63) / 64;   // 782
  const int edge_tiles = N_EDGES / 64;          // 12500 exact

  for (int i = 0; i < NBLK; i++) {
    xgemm_kernel<<<node_tiles, 256, 0, stream>>>(h, wp_lin1 + (size_t)i * FRAG_ELEMS, x);
    zero_kernel<<<(N_NODES * NF / 4 + 255) / 256, 256, 0, stream>>>((float4*)agg, N_NODES * NF / 4);
    edge_kernel<<<edge_tiles, 256, 0, stream>>>(ea, ei, elen,
        wp_nw1 + (size_t)i * FRAG_ELEMS, nn_b1 + (size_t)i * NF,
        wp_nw2 + (size_t)i * FRAG_ELEMS, nn_b2 + (size_t)i * NF,
        x, agg);
    node_kernel<<<node_tiles, 256, 0, stream>>>(agg,
        wp_l2 + (size_t)i * FRAG_ELEMS, lin2_b + (size_t)i * HID,
        wp_l + (size_t)i * FRAG_ELEMS, lin_b + (size_t)i * HID,
        h);
  }
}

// Round 3
// 2580.442 us; speedup vs baseline: 1.3277x; 1.1682x over previous
//
#include <hip/hip_runtime.h>
#include <cstddef>

typedef __bf16 bf16;
typedef bf16 bf16x4 __attribute__((ext_vector_type(4)));
typedef bf16 bf16x8 __attribute__((ext_vector_type(8)));
typedef float f32x4 __attribute__((ext_vector_type(4)));

#define N_NODES 50000
#define N_EDGES 800000
#define HID 128
#define NF 128
#define EC 100
#define NBLK 6
#define IN_DIM 5
#define LN2 0.69314718055994530942f
#define LDST 136          // bf16 stride: 128 + 8 pad (16B-aligned rows, bank-skewed)
#define MST 136           // fp32 msg stride: row step = 136 dwords ≡ 8 mod 32 -> 2-way max
#define FRAG_ELEMS 16384  // one repacked 128x128 weight: 2048 frags x 8 bf16
#define HIST_PAD 50176    // 50000 rounded to 256*196, float4-zeroable

__device__ __forceinline__ float ssp_f(float v) {
  float e = __expf(-fabsf(v));
  return fmaxf(v, 0.0f) + __logf(1.0f + e) - LN2;
}

__device__ __forceinline__ f32x4 zero4() {
  f32x4 v; v[0] = 0.f; v[1] = 0.f; v[2] = 0.f; v[3] = 0.f; return v;
}

// ---------------- weight repack (once per launch) ----------------
// [K<=128 x 128] fp32 -> per-lane MFMA B-fragment order (bf16).
// Consumer: Bf[nt][ks] elem j = W[k=ks*32+quad*8+j][n=wave*32+nt*16+lanelo].
__global__ void repack_kernel(const float* __restrict__ src, bf16* __restrict__ dst,
                              int K, int srcStride) {
  const int m = blockIdx.x;
  const float* s = src + (size_t)m * srcStride;
  bf16* d = dst + (size_t)m * FRAG_ELEMS;
  const int tid = threadIdx.x;
  const int wave = tid >> 6, lane = tid & 63;
  const int quad = lane >> 4, lanelo = lane & 15;
  const int col = wave * 32 + lanelo;
#pragma unroll
  for (int nt = 0; nt < 2; nt++)
#pragma unroll
    for (int ks = 0; ks < 4; ks++) {
      bf16x8 f;
#pragma unroll
      for (int j = 0; j < 8; j++) {
        int k = ks * 32 + quad * 8 + j;
        f[j] = (bf16)((k < K) ? s[(size_t)k * 128 + col + nt * 16] : 0.0f);
      }
      *(bf16x8*)&d[(size_t)(((wave * 2 + nt) * 4 + ks) * 64 + lane) * 8] = f;
    }
}

// ---------------- counting sort of edges by dst (once per launch) ----------------
__global__ void hist_kernel(const int* __restrict__ ei, int* __restrict__ hist) {
  int e = blockIdx.x * 256 + threadIdx.x;
  if (e < N_EDGES) atomicAdd(&hist[ei[N_EDGES + e]], 1);
}

// per-block exclusive scan; block totals to bsums
__global__ void scan_blocks_kernel(const int* __restrict__ in, int* __restrict__ out,
                                   int* __restrict__ bsums) {
  __shared__ int s[256];
  int i = blockIdx.x * 256 + threadIdx.x;
  int v = in[i];
  s[threadIdx.x] = v;
  __syncthreads();
#pragma unroll
  for (int off = 1; off < 256; off <<= 1) {
    int t = (threadIdx.x >= off) ? s[threadIdx.x - off] : 0;
    __syncthreads();
    s[threadIdx.x] += t;
    __syncthreads();
  }
  out[i] = s[threadIdx.x] - v;  // exclusive
  if (threadIdx.x == 255) bsums[blockIdx.x] = s[255];
}

__global__ void scan_bsums_kernel(int* __restrict__ bsums, int nb) {
  __shared__ int s[256];
  int v = (threadIdx.x < nb) ? bsums[threadIdx.x] : 0;
  s[threadIdx.x] = v;
  __syncthreads();
#pragma unroll
  for (int off = 1; off < 256; off <<= 1) {
    int t = (threadIdx.x >= off) ? s[threadIdx.x - off] : 0;
    __syncthreads();
    s[threadIdx.x] += t;
    __syncthreads();
  }
  if (threadIdx.x < nb) bsums[threadIdx.x] = s[threadIdx.x] - v;  // exclusive
}

// add scanned block offsets; also produce mutable cursor copy for scatter
__global__ void scan_add_kernel(int* __restrict__ out, const int* __restrict__ bsums,
                                int* __restrict__ cursor) {
  int i = blockIdx.x * 256 + threadIdx.x;
  int v = out[i] + bsums[blockIdx.x];
  out[i] = v;
  cursor[i] = v;
}

__global__ void scatter_kernel(const int* __restrict__ ei, int* __restrict__ cursor,
                               int* __restrict__ perm) {
  int e = blockIdx.x * 256 + threadIdx.x;
  if (e < N_EDGES) {
    int d = ei[N_EDGES + e];
    int pos = atomicAdd(&cursor[d], 1);
    perm[pos] = e;
  }
}

// ---------------- misc ----------------
__global__ void embed_kernel(const float* __restrict__ z,
                             const float* __restrict__ ew,
                             const float* __restrict__ eb,
                             float* __restrict__ h) {
  int i = blockIdx.x * 256 + threadIdx.x;
  if (i >= N_NODES * HID) return;
  int n = i >> 7, c = i & 127;
  const float* zr = z + (size_t)n * (IN_DIM + HID);
  float acc = eb[c] + zr[IN_DIM + c];
#pragma unroll
  for (int k = 0; k < IN_DIM; k++) acc = fmaf(zr[k], ew[k * HID + c], acc);
  h[i] = acc;
}

__global__ void zero_kernel(float4* __restrict__ p, int n4) {
  int i = blockIdx.x * 256 + threadIdx.x;
  if (i < n4) p[i] = make_float4(0.f, 0.f, 0.f, 0.f);
}

// ---------------- x = h @ w (one 64-row tile per block) ----------------
__global__ __launch_bounds__(256, 4)
void xgemm_kernel(const float* __restrict__ hmat,
                  const bf16* __restrict__ wf,
                  float* __restrict__ xout) {
  __shared__ bf16 sA[64 * LDST];
  const int tid = threadIdx.x;
  const int wave = tid >> 6, lane = tid & 63;
  const int quad = lane >> 4, lanelo = lane & 15;
  const int ncol0 = wave * 32;
  const int row0 = blockIdx.x * 64;

  bf16x8 Bf[2][4];
#pragma unroll
  for (int nt = 0; nt < 2; nt++)
#pragma unroll
    for (int ks = 0; ks < 4; ks++)
      Bf[nt][ks] = *(const bf16x8*)&wf[(size_t)(((wave * 2 + nt) * 4 + ks) * 64 + lane) * 8];

#pragma unroll
  for (int it = 0; it < 8; it++) {
    int idx = tid + it * 256;
    int r = idx >> 5, c4 = idx & 31;
    int grow = row0 + r;
    float4 v = (grow < N_NODES) ? *(const float4*)&hmat[(size_t)grow * HID + c4 * 4]
                                : make_float4(0.f, 0.f, 0.f, 0.f);
    bf16x4 o; o[0] = (bf16)v.x; o[1] = (bf16)v.y; o[2] = (bf16)v.z; o[3] = (bf16)v.w;
    *(bf16x4*)&sA[r * LDST + c4 * 4] = o;
  }
  __syncthreads();

  f32x4 acc[4][2];
#pragma unroll
  for (int mt = 0; mt < 4; mt++)
#pragma unroll
    for (int nt = 0; nt < 2; nt++) acc[mt][nt] = zero4();
#pragma unroll
  for (int ks = 0; ks < 4; ks++) {
    bf16x8 a[4];
#pragma unroll
    for (int mt = 0; mt < 4; mt++)
      a[mt] = *(const bf16x8*)&sA[(mt * 16 + lanelo) * LDST + ks * 32 + quad * 8];
#pragma unroll
    for (int mt = 0; mt < 4; mt++)
#pragma unroll
      for (int nt = 0; nt < 2; nt++)
        acc[mt][nt] = __builtin_amdgcn_mfma_f32_16x16x32_bf16(a[mt], Bf[nt][ks], acc[mt][nt], 0, 0, 0);
  }
#pragma unroll
  for (int mt = 0; mt < 4; mt++)
#pragma unroll
    for (int r = 0; r < 4; r++) {
      int grow = row0 + mt * 16 + quad * 4 + r;
      if (grow < N_NODES) {
#pragma unroll
        for (int nt = 0; nt < 2; nt++)
          xout[(size_t)grow * NF + ncol0 + nt * 16 + lanelo] = acc[mt][nt][r];
      }
    }
}

// ---------------- fused edge MLP + gather + segmented scatter-reduce ----------------
// Edges processed in dst-sorted order via perm. After GEMM2, msg rows go to LDS
// (fp32, mask folded); per-column segmented reduction emits ONE atomic per
// (dst-group x column) instead of per (edge x column).
__global__ __launch_bounds__(256, 4)
void edge_kernel(const float* __restrict__ ea,
                 const int* __restrict__ ei,
                 const float* __restrict__ elen,
                 const int* __restrict__ perm,
                 const bf16* __restrict__ w1f, const float* __restrict__ b1,
                 const bf16* __restrict__ w2f, const float* __restrict__ b2,
                 const float* __restrict__ x,
                 float* __restrict__ agg) {
  // bf16 GEMM tile and fp32 msg tile alias the same LDS (used in disjoint phases)
  __shared__ alignas(16) char s_buf[64 * MST * 4];  // 34816 B
  bf16* sA = (bf16*)s_buf;
  float* s_msg = (float*)s_buf;
  __shared__ int s_src[64];
  __shared__ int s_dst[64];
  __shared__ float s_c[64];

  const int tid = threadIdx.x;
  const int wave = tid >> 6, lane = tid & 63;
  const int quad = lane >> 4, lanelo = lane & 15;
  const int ncol0 = wave * 32;
  const int e0 = blockIdx.x * 64;

  bf16x8 Bf1[2][4], Bf2[2][4];
#pragma unroll
  for (int nt = 0; nt < 2; nt++)
#pragma unroll
    for (int ks = 0; ks < 4; ks++) {
      size_t fo = (size_t)(((wave * 2 + nt) * 4 + ks) * 64 + lane) * 8;
      Bf1[nt][ks] = *(const bf16x8*)&w1f[fo];
      Bf2[nt][ks] = *(const bf16x8*)&w2f[fo];
    }
  float bias1[2], bias2[2];
#pragma unroll
  for (int nt = 0; nt < 2; nt++) {
    bias1[nt] = b1[ncol0 + nt * 16 + lanelo];
    bias2[nt] = b2[ncol0 + nt * 16 + lanelo];
  }

  // stage permuted edge_attr tile: 64 x 100 fp32 -> 64 x 128 bf16 (cols 100..127 = 0)
#pragma unroll
  for (int it = 0; it < 8; it++) {
    int idx = tid + it * 256;
    int r = idx >> 5, c4 = idx & 31;
    int pe = perm[e0 + r];  // redundant across the 32-thread row group; L1-served
    float4 v = make_float4(0.f, 0.f, 0.f, 0.f);
    if (c4 < 25) v = *(const float4*)&ea[(size_t)pe * EC + c4 * 4];
    bf16x4 o; o[0] = (bf16)v.x; o[1] = (bf16)v.y; o[2] = (bf16)v.z; o[3] = (bf16)v.w;
    *(bf16x4*)&sA[r * LDST + c4 * 4] = o;
  }
  if (tid < 64) {
    int pe = perm[e0 + tid];
    s_src[tid] = ei[pe];
    s_dst[tid] = ei[N_EDGES + pe];
    float L = elen[pe];
    s_c[tid] = (L <= 10.0f && L >= 0.0f) ? 1.0f : 0.0f;
  }
  __syncthreads();

  // GEMM1: t = ea @ w1
  f32x4 acc[4][2];
#pragma unroll
  for (int mt = 0; mt < 4; mt++)
#pragma unroll
    for (int nt = 0; nt < 2; nt++) acc[mt][nt] = zero4();
#pragma unroll
  for (int ks = 0; ks < 4; ks++) {
    bf16x8 a[4];
#pragma unroll
    for (int mt = 0; mt < 4; mt++)
      a[mt] = *(const bf16x8*)&sA[(mt * 16 + lanelo) * LDST + ks * 32 + quad * 8];
#pragma unroll
    for (int mt = 0; mt < 4; mt++)
#pragma unroll
      for (int nt = 0; nt < 2; nt++)
        acc[mt][nt] = __builtin_amdgcn_mfma_f32_16x16x32_bf16(a[mt], Bf1[nt][ks], acc[mt][nt], 0, 0, 0);
  }
  __syncthreads();  // done reading ea-tile

  // ssp, C-layout -> A-layout, in place
#pragma unroll
  for (int mt = 0; mt < 4; mt++)
#pragma unroll
    for (int nt = 0; nt < 2; nt++)
#pragma unroll
      for (int r = 0; r < 4; r++) {
        float v = ssp_f(acc[mt][nt][r] + bias1[nt]);
        sA[(mt * 16 + quad * 4 + r) * LDST + ncol0 + nt * 16 + lanelo] = (bf16)v;
      }
  __syncthreads();

  // GEMM2: W = t @ w2
#pragma unroll
  for (int mt = 0; mt < 4; mt++)
#pragma unroll
    for (int nt = 0; nt < 2; nt++) acc[mt][nt] = zero4();
#pragma unroll
  for (int ks = 0; ks < 4; ks++) {
    bf16x8 a[4];
#pragma unroll
    for (int mt = 0; mt < 4; mt++)
      a[mt] = *(const bf16x8*)&sA[(mt * 16 + lanelo) * LDST + ks * 32 + quad * 8];
#pragma unroll
    for (int mt = 0; mt < 4; mt++)
#pragma unroll
      for (int nt = 0; nt < 2; nt++)
        acc[mt][nt] = __builtin_amdgcn_mfma_f32_16x16x32_bf16(a[mt], Bf2[nt][ks], acc[mt][nt], 0, 0, 0);
  }
  __syncthreads();  // all waves done with sA before fp32 msg overwrite (aliased)

  // msg = x[src] * W * C -> LDS (fp32). Masked rows write 0 and skip the gather.
#pragma unroll
  for (int mt = 0; mt < 4; mt++)
#pragma unroll
    for (int r = 0; r < 4; r++) {
      int row = mt * 16 + quad * 4 + r;
      float ce = s_c[row];
      int srcn = s_src[row];
#pragma unroll
      for (int nt = 0; nt < 2; nt++) {
        int col = ncol0 + nt * 16 + lanelo;
        float g = (ce != 0.0f) ? x[(size_t)srcn * NF + col] : 0.0f;
        float wv = acc[mt][nt][r] + bias2[nt];
        s_msg[row * MST + col] = wv * g;
      }
    }
  __syncthreads();

  // segmented per-column reduction: thread t owns column t&127, rows rhalf*32..+31.
  // s_dst is sorted -> few group boundaries -> ~one atomic per (group x col).
  {
    const int col = tid & 127;
    const int r0 = (tid >> 7) * 32;
    float acc2 = 0.0f;
    int prev = s_dst[r0];
    for (int r = r0; r < r0 + 32; r++) {
      int d = s_dst[r];              // wave-uniform per iteration
      if (d != prev) {
        atomicAdd(&agg[(size_t)prev * NF + col], acc2);
        acc2 = 0.0f;
        prev = d;
      }
      acc2 += s_msg[r * MST + col];
    }
    atomicAdd(&agg[(size_t)prev * NF + col], acc2);
  }
}

// ---------------- h += ssp(agg@w1+b1)@w2 + b2 ----------------
__global__ __launch_bounds__(256, 4)
void node_kernel(const float* __restrict__ agg,
                 const bf16* __restrict__ w1f, const float* __restrict__ b1,
                 const bf16* __restrict__ w2f, const float* __restrict__ b2,
                 float* __restrict__ h) {
  __shared__ bf16 sA[64 * LDST];
  const int tid = threadIdx.x;
  const int wave = tid >> 6, lane = tid & 63;
  const int quad = lane >> 4, lanelo = lane & 15;
  const int ncol0 = wave * 32;
  const int row0 = blockIdx.x * 64;

  bf16x8 Bf1[2][4], Bf2[2][4];
#pragma unroll
  for (int nt = 0; nt < 2; nt++)
#pragma unroll
    for (int ks = 0; ks < 4; ks++) {
      size_t fo = (size_t)(((wave * 2 + nt) * 4 + ks) * 64 + lane) * 8;
      Bf1[nt][ks] = *(const bf16x8*)&w1f[fo];
      Bf2[nt][ks] = *(const bf16x8*)&w2f[fo];
    }
  float bias1[2], bias2[2];
#pragma unroll
  for (int nt = 0; nt < 2; nt++) {
    bias1[nt] = b1[ncol0 + nt * 16 + lanelo];
    bias2[nt] = b2[ncol0 + nt * 16 + lanelo];
  }

#pragma unroll
  for (int it = 0; it < 8; it++) {
    int idx = tid + it * 256;
    int r = idx >> 5, c4 = idx & 31;
    int grow = row0 + r;
    float4 v = (grow < N_NODES) ? *(const float4*)&agg[(size_t)grow * NF + c4 * 4]
                                : make_float4(0.f, 0.f, 0.f, 0.f);
    bf16x4 o; o[0] = (bf16)v.x; o[1] = (bf16)v.y; o[2] = (bf16)v.z; o[3] = (bf16)v.w;
    *(bf16x4*)&sA[r * LDST + c4 * 4] = o;
  }
  __syncthreads();

  f32x4 acc[4][2];
#pragma unroll
  for (int mt = 0; mt < 4; mt++)
#pragma unroll
    for (int nt = 0; nt < 2; nt++) acc[mt][nt] = zero4();
#pragma unroll
  for (int ks = 0; ks < 4; ks++) {
    bf16x8 a[4];
#pragma unroll
    for (int mt = 0; mt < 4; mt++)
      a[mt] = *(const bf16x8*)&sA[(mt * 16 + lanelo) * LDST + ks * 32 + quad * 8];
#pragma unroll
    for (int mt = 0; mt < 4; mt++)
#pragma unroll
      for (int nt = 0; nt < 2; nt++)
        acc[mt][nt] = __builtin_amdgcn_mfma_f32_16x16x32_bf16(a[mt], Bf1[nt][ks], acc[mt][nt], 0, 0, 0);
  }
  __syncthreads();

#pragma unroll
  for (int mt = 0; mt < 4; mt++)
#pragma unroll
    for (int nt = 0; nt < 2; nt++)
#pragma unroll
      for (int r = 0; r < 4; r++) {
        float v = ssp_f(acc[mt][nt][r] + bias1[nt]);
        sA[(mt * 16 + quad * 4 + r) * LDST + ncol0 + nt * 16 + lanelo] = (bf16)v;
      }
  __syncthreads();

#pragma unroll
  for (int mt = 0; mt < 4; mt++)
#pragma unroll
    for (int nt = 0; nt < 2; nt++) acc[mt][nt] = zero4();
#pragma unroll
  for (int ks = 0; ks < 4; ks++) {
    bf16x8 a[4];
#pragma unroll
    for (int mt = 0; mt < 4; mt++)
      a[mt] = *(const bf16x8*)&sA[(mt * 16 + lanelo) * LDST + ks * 32 + quad * 8];
#pragma unroll
    for (int mt = 0; mt < 4; mt++)
#pragma unroll
      for (int nt = 0; nt < 2; nt++)
        acc[mt][nt] = __builtin_amdgcn_mfma_f32_16x16x32_bf16(a[mt], Bf2[nt][ks], acc[mt][nt], 0, 0, 0);
  }
#pragma unroll
  for (int mt = 0; mt < 4; mt++)
#pragma unroll
    for (int r = 0; r < 4; r++) {
      int grow = row0 + mt * 16 + quad * 4 + r;
      if (grow < N_NODES) {
#pragma unroll
        for (int nt = 0; nt < 2; nt++) {
          int col = ncol0 + nt * 16 + lanelo;
          size_t off = (size_t)grow * HID + col;
          h[off] += acc[mt][nt][r] + bias2[nt];
        }
      }
    }
}

extern "C" void kernel_launch(void* const* d_in, const int* in_sizes, int n_in,
                              void* d_out, int out_size, void* d_ws, size_t ws_size,
                              hipStream_t stream) {
  const float* z        = (const float*)d_in[0];
  const int*   ei       = (const int*)d_in[1];
  const float* elen     = (const float*)d_in[2];
  const float* ea       = (const float*)d_in[3];
  const float* emblin_w = (const float*)d_in[4];
  const float* emblin_b = (const float*)d_in[5];
  const float* lin1_w   = (const float*)d_in[6];
  const float* nn_w1    = (const float*)d_in[7];
  const float* nn_b1    = (const float*)d_in[8];
  const float* nn_w2    = (const float*)d_in[9];
  const float* nn_b2    = (const float*)d_in[10];
  const float* lin2_w   = (const float*)d_in[11];
  const float* lin2_b   = (const float*)d_in[12];
  const float* lin_w    = (const float*)d_in[13];
  const float* lin_b    = (const float*)d_in[14];

  float* h   = (float*)d_out;                        // 50000 x 128
  // ---- workspace layout ----
  char* base = (char*)d_ws;
  float* x    = (float*)base;                        base += (size_t)N_NODES * NF * 4;   // 25.6 MB
  float* agg  = (float*)base;                        base += (size_t)N_NODES * NF * 4;   // 25.6 MB
  bf16* wp    = (bf16*)base;                         base += (size_t)5 * NBLK * FRAG_ELEMS * 2; // 0.98 MB
  int* hist   = (int*)base;                          base += (size_t)HIST_PAD * 4;       // offsets (scanned)
  int* cursor = (int*)base;                          base += (size_t)HIST_PAD * 4;
  int* bsums  = (int*)base;                          base += 1024;
  int* perm   = (int*)base;                          base += (size_t)N_EDGES * 4;        // 3.2 MB

  bf16* wp_lin1 = wp;
  bf16* wp_nw1  = wp + 1 * (size_t)NBLK * FRAG_ELEMS;
  bf16* wp_nw2  = wp + 2 * (size_t)NBLK * FRAG_ELEMS;
  bf16* wp_l2   = wp + 3 * (size_t)NBLK * FRAG_ELEMS;
  bf16* wp_l    = wp + 4 * (size_t)NBLK * FRAG_ELEMS;

  // weight repack
  repack_kernel<<<NBLK, 256, 0, stream>>>(lin1_w, wp_lin1, HID, HID * NF);
  repack_kernel<<<NBLK, 256, 0, stream>>>(nn_w1, wp_nw1, EC, EC * NF);
  repack_kernel<<<NBLK, 256, 0, stream>>>(nn_w2, wp_nw2, NF, NF * NF);
  repack_kernel<<<NBLK, 256, 0, stream>>>(lin2_w, wp_l2, NF, NF * HID);
  repack_kernel<<<NBLK, 256, 0, stream>>>(lin_w, wp_l, HID, HID * HID);

  // counting sort of edges by dst
  const int nb = HIST_PAD / 256;  // 196
  zero_kernel<<<(HIST_PAD / 4 + 255) / 256, 256, 0, stream>>>((float4*)hist, HIST_PAD / 4);
  hist_kernel<<<(N_EDGES + 255) / 256, 256, 0, stream>>>(ei, hist);
  scan_blocks_kernel<<<nb, 256, 0, stream>>>(hist, hist, bsums);
  scan_bsums_kernel<<<1, 256, 0, stream>>>(bsums, nb);
  scan_add_kernel<<<nb, 256, 0, stream>>>(hist, bsums, cursor);
  scatter_kernel<<<(N_EDGES + 255) / 256, 256, 0, stream>>>(ei, cursor, perm);

  embed_kernel<<<(N_NODES * HID + 255) / 256, 256, 0, stream>>>(z, emblin_w, emblin_b, h);

  const int node_tiles = (N_NODES + 63) / 64;   // 782
  const int edge_tiles = N_EDGES / 64;          // 12500 exact

  for (int i = 0; i < NBLK; i++) {
    xgemm_kernel<<<node_tiles, 256, 0, stream>>>(h, wp_lin1 + (size_t)i * FRAG_ELEMS, x);
    zero_kernel<<<(N_NODES * NF / 4 + 255) / 256, 256, 0, stream>>>((float4*)agg, N_NODES * NF / 4);
    edge_kernel<<<edge_tiles, 256, 0, stream>>>(ea, ei, elen, perm,
        wp_nw1 + (size_t)i * FRAG_ELEMS, nn_b1 + (size_t)i * NF,
        wp_nw2 + (size_t)i * FRAG_ELEMS, nn_b2 + (size_t)i * NF,
        x, agg);
    node_kernel<<<node_tiles, 256, 0, stream>>>(agg,
        wp_l2 + (size_t)i * FRAG_ELEMS, lin2_b + (size_t)i * HID,
        wp_l + (size_t)i * FRAG_ELEMS, lin_b + (size_t)i * HID,
        h);
  }
}